// Round 6
// baseline (114.537 us; speedup 1.0000x reference)
//
#include <hip/hip_runtime.h>

#define FDIM 128
#define EMB 32
#define LDST 36

// ---------------- K1: xe = x @ W  (f32 in, f32 out) ----------------
__global__ __launch_bounds__(256) void k_gemm(const float* __restrict__ x,
                                              const float* __restrict__ Wm,
                                              float* __restrict__ xe) {
    __shared__ float sW[FDIM * EMB];
    const int t = threadIdx.x;
#pragma unroll
    for (int i = 0; i < (FDIM * EMB) / (256 * 4); ++i) {
        int idx = (t + i * 256) * 4;
        *(float4*)(sW + idx) = *(const float4*)(Wm + idx);
    }
    __syncthreads();

    const int r0 = blockIdx.x * 128 + (t >> 3) * 4;
    const int e0 = (t & 7) * 4;

    float acc[4][4];
#pragma unroll
    for (int i = 0; i < 4; ++i)
#pragma unroll
        for (int j = 0; j < 4; ++j) acc[i][j] = 0.f;

    for (int k = 0; k < FDIM; k += 4) {
        float4 w0 = *(const float4*)(sW + (k + 0) * EMB + e0);
        float4 w1 = *(const float4*)(sW + (k + 1) * EMB + e0);
        float4 w2 = *(const float4*)(sW + (k + 2) * EMB + e0);
        float4 w3 = *(const float4*)(sW + (k + 3) * EMB + e0);
#pragma unroll
        for (int rr = 0; rr < 4; ++rr) {
            float4 xq = *(const float4*)(x + (size_t)(r0 + rr) * FDIM + k);
            acc[rr][0] += xq.x * w0.x + xq.y * w1.x + xq.z * w2.x + xq.w * w3.x;
            acc[rr][1] += xq.x * w0.y + xq.y * w1.y + xq.z * w2.y + xq.w * w3.y;
            acc[rr][2] += xq.x * w0.z + xq.y * w1.z + xq.z * w2.z + xq.w * w3.z;
            acc[rr][3] += xq.x * w0.w + xq.y * w1.w + xq.z * w2.w + xq.w * w3.w;
        }
    }

#pragma unroll
    for (int rr = 0; rr < 4; ++rr) {
        const size_t r = (size_t)(r0 + rr);
        float4 o; o.x = acc[rr][0]; o.y = acc[rr][1]; o.z = acc[rr][2]; o.w = acc[rr][3];
        *(float4*)(xe + r * EMB + e0) = o;
    }
}

// ---------------- K2a/K2b: centroid + scale (unchanged) ----------------
__global__ __launch_bounds__(256) void k_stats_a(const float* __restrict__ xe,
                                                 float* __restrict__ psum,
                                                 float* __restrict__ pmin,
                                                 float* __restrict__ pmax) {
    __shared__ float rs[256], rmn[256], rmx[256];
    const int t = threadIdx.x;
    const int d = t & 31, rg = t >> 5;
    const int r0 = blockIdx.x * 32;

    float s = 0.f, mn = 3.4e38f, mx = -3.4e38f;
#pragma unroll
    for (int it = 0; it < 4; ++it) {
        float v = xe[(size_t)(r0 + rg + it * 8) * EMB + d];
        s += v; mn = fminf(mn, v); mx = fmaxf(mx, v);
    }
    rs[t] = s; rmn[t] = mn; rmx[t] = mx;
    __syncthreads();
#pragma unroll
    for (int st = 128; st >= 32; st >>= 1) {
        if (t < st) {
            rs[t] += rs[t + st];
            rmn[t] = fminf(rmn[t], rmn[t + st]);
            rmx[t] = fmaxf(rmx[t], rmx[t + st]);
        }
        __syncthreads();
    }
    if (t < 32) {
        psum[blockIdx.x * 32 + t] = rs[t];
        pmin[blockIdx.x * 32 + t] = rmn[t];
        pmax[blockIdx.x * 32 + t] = rmx[t];
    }
}

__global__ __launch_bounds__(64) void k_stats_b(const float* __restrict__ psum,
                                                const float* __restrict__ pmin,
                                                const float* __restrict__ pmax,
                                                int nb, int n,
                                                float* __restrict__ stats) {
    const int t = threadIdx.x;
    const int d = t & 31;
    float s = 0.f, mn = 3.4e38f, mx = -3.4e38f;
    for (int b = 0; b < nb; ++b) {
        s += psum[b * 32 + d];
        mn = fminf(mn, pmin[b * 32 + d]);
        mx = fmaxf(mx, pmax[b * 32 + d]);
    }
    const float c = s / (float)n;
    float dev = fmaxf(mx - c, c - mn);
#pragma unroll
    for (int off = 16; off >= 1; off >>= 1)
        dev = fmaxf(dev, __shfl_xor(dev, off, 32));
    if (t < 32) stats[t] = c;
    if (t == 0) stats[EMB] = 0.9f / dev;
}

// ---------------- K3: persistent fused pairwise+sigmoid+index kernel ----------------
// 1024 resident blocks, each processes `tpb` 64x64 tiles with a software
// pipeline: raw s_barrier (NO vmcnt drain) so iteration k+1's compute
// overlaps iteration k's store drain. Both LDS tiles XOR-swizzled
// (d ^= ((row>>2)&7)<<2): A-reads, B-reads conflict-free.
__global__ __launch_bounds__(256, 4) void k_edges_p(const float* __restrict__ xe,
                                                    const float* __restrict__ stats,
                                                    const float* __restrict__ tptr,
                                                    const float* __restrict__ thptr,
                                                    float* __restrict__ wts,
                                                    float* __restrict__ srcp,
                                                    float* __restrict__ dstp,
                                                    int n, int ntiles, int tpb) {
    __shared__ float shA[64 * LDST];
    __shared__ float shB[64 * LDST];
    __shared__ float sqA[64], sqB[64];

    const int t = threadIdx.x;
    const int t0 = blockIdx.x * tpb;
    int cnt = ntiles - t0;
    if (cnt <= 0) return;
    if (cnt > tpb) cnt = tpb;

    const int tprow = n >> 6;           // tiles per row = 16
    const int tpg = tprow * tprow;      // tiles per graph = 256

    const float scale = stats[EMB];
    const float T = *tptr;
    const float TH = fabsf(*thptr);

    // staging role: 128 threads per side; each stages half a row (16 floats)
    const int sideB = (t >= 128);
    const int tid2 = t & 127;
    const int rid = tid2 >> 1;
    const int half = tid2 & 1;
    const int skey = ((rid >> 2) & 7) << 2;
    const int cbase = half * 16;

    const float4 cen0 = *(const float4*)(stats + cbase + 0);
    const float4 cen1 = *(const float4*)(stats + cbase + 4);
    const float4 cen2 = *(const float4*)(stats + cbase + 8);
    const float4 cen3 = *(const float4*)(stats + cbase + 12);

    // compute role
    const int ti = t >> 4, tj = t & 15;
    const int akey = (ti & 7) << 2;
    const int bkey = (tj & 7) << 2;

    // ---- helpers as macros (keep everything in registers) ----
#define COORDS(tt, g_, i0_, j0_)                                              \
    {                                                                         \
        g_ = (tt) / tpg;                                                      \
        int r_ = (tt) - g_ * tpg;                                             \
        i0_ = (r_ / tprow) * 64;                                              \
        j0_ = (r_ - (r_ / tprow) * tprow) * 64;                               \
    }

#define LOADT(g_, i0_, j0_, l0, l1, l2, l3)                                   \
    {                                                                         \
        const int row_ = (sideB ? (j0_) : (i0_)) + rid;                       \
        const float* p_ = xe + ((size_t)((g_)*n + row_)) * EMB + cbase;       \
        l0 = *(const float4*)(p_ + 0);                                        \
        l1 = *(const float4*)(p_ + 4);                                        \
        l2 = *(const float4*)(p_ + 8);                                        \
        l3 = *(const float4*)(p_ + 12);                                       \
    }

#define STAGE(l0, l1, l2, l3)                                                 \
    {                                                                         \
        l0.x = (l0.x - cen0.x) * scale; l0.y = (l0.y - cen0.y) * scale;       \
        l0.z = (l0.z - cen0.z) * scale; l0.w = (l0.w - cen0.w) * scale;       \
        l1.x = (l1.x - cen1.x) * scale; l1.y = (l1.y - cen1.y) * scale;       \
        l1.z = (l1.z - cen1.z) * scale; l1.w = (l1.w - cen1.w) * scale;       \
        l2.x = (l2.x - cen2.x) * scale; l2.y = (l2.y - cen2.y) * scale;       \
        l2.z = (l2.z - cen2.z) * scale; l2.w = (l2.w - cen2.w) * scale;       \
        l3.x = (l3.x - cen3.x) * scale; l3.y = (l3.y - cen3.y) * scale;       \
        l3.z = (l3.z - cen3.z) * scale; l3.w = (l3.w - cen3.w) * scale;       \
        float ps_ = l0.x*l0.x + l0.y*l0.y + l0.z*l0.z + l0.w*l0.w             \
                  + l1.x*l1.x + l1.y*l1.y + l1.z*l1.z + l1.w*l1.w             \
                  + l2.x*l2.x + l2.y*l2.y + l2.z*l2.z + l2.w*l2.w             \
                  + l3.x*l3.x + l3.y*l3.y + l3.z*l3.z + l3.w*l3.w;            \
        float tot_ = ps_ + __shfl_xor(ps_, 1);                                \
        float* sh_ = sideB ? shB : shA;                                       \
        *(float4*)(sh_ + rid * LDST + ((cbase + 0) ^ skey))  = l0;            \
        *(float4*)(sh_ + rid * LDST + ((cbase + 4) ^ skey))  = l1;            \
        *(float4*)(sh_ + rid * LDST + ((cbase + 8) ^ skey))  = l2;            \
        *(float4*)(sh_ + rid * LDST + ((cbase + 12) ^ skey)) = l3;            \
        if (half == 0) { if (sideB) sqB[rid] = tot_; else sqA[rid] = tot_; }  \
    }

#define RAWBAR()                                                              \
    {                                                                         \
        __builtin_amdgcn_sched_barrier(0);                                    \
        __builtin_amdgcn_s_barrier();                                         \
        __builtin_amdgcn_sched_barrier(0);                                    \
    }

    // ---- prologue: stage tile t0 ----
    {
        int g, i0, j0;
        COORDS(t0, g, i0, j0);
        float4 l0, l1, l2, l3;
        LOADT(g, i0, j0, l0, l1, l2, l3);
        STAGE(l0, l1, l2, l3);
    }
    asm volatile("s_waitcnt lgkmcnt(0)" ::: "memory");
    RAWBAR();

    for (int k = 0; k < cnt; ++k) {
        const int tt = t0 + k;
        int g, i0, j0;
        COORDS(tt, g, i0, j0);

        // prefetch next tile's rows into registers (counted vmcnt at use)
        const int have = (k + 1 < cnt);
        float4 l0, l1, l2, l3;
        if (have) {
            int g2, i02, j02;
            COORDS(tt + 1, g2, i02, j02);
            LOADT(g2, i02, j02, l0, l1, l2, l3);
        }

        // ---- compute tile tt from LDS ----
        float acc[4][4];
#pragma unroll
        for (int i = 0; i < 4; ++i)
#pragma unroll
            for (int j = 0; j < 4; ++j) acc[i][j] = 0.f;

#pragma unroll
        for (int d = 0; d < EMB; d += 4) {
            float4 a[4], b[4];
            const int da = d ^ akey;
            const int db = d ^ bkey;
#pragma unroll
            for (int u = 0; u < 4; ++u)
                a[u] = *(const float4*)(shA + (ti * 4 + u) * LDST + da);
#pragma unroll
            for (int v = 0; v < 4; ++v)
                b[v] = *(const float4*)(shB + (tj * 4 + v) * LDST + db);
#pragma unroll
            for (int u = 0; u < 4; ++u)
#pragma unroll
                for (int v = 0; v < 4; ++v)
                    acc[u][v] += a[u].x * b[v].x + a[u].y * b[v].y +
                                 a[u].z * b[v].z + a[u].w * b[v].w;
        }

        const int gn = g * n;
        const size_t gbase = (size_t)g * n * n;
        const float4 sq4 = *(const float4*)(sqB + tj * 4);
        const float dbase = (float)(gn + j0 + tj * 4);
        float4 dst4; dst4.x = dbase; dst4.y = dbase + 1.f;
        dst4.z = dbase + 2.f; dst4.w = dbase + 3.f;

#pragma unroll
        for (int u = 0; u < 4; ++u) {
            const int row = i0 + ti * 4 + u;
            const float sa = sqA[ti * 4 + u];
            const size_t off = gbase + (size_t)row * n + j0 + tj * 4;

            float4 w;
            float D0 = fmaxf(sa + sq4.x - 2.f * acc[u][0], 0.f);
            float D1 = fmaxf(sa + sq4.y - 2.f * acc[u][1], 0.f);
            float D2 = fmaxf(sa + sq4.z - 2.f * acc[u][2], 0.f);
            float D3 = fmaxf(sa + sq4.w - 2.f * acc[u][3], 0.f);
            w.x = __builtin_amdgcn_rcpf(1.f + __expf(-(T * (TH - D0))));
            w.y = __builtin_amdgcn_rcpf(1.f + __expf(-(T * (TH - D1))));
            w.z = __builtin_amdgcn_rcpf(1.f + __expf(-(T * (TH - D2))));
            w.w = __builtin_amdgcn_rcpf(1.f + __expf(-(T * (TH - D3))));
            *(float4*)(wts + off) = w;

            const float sv = (float)(gn + row);
            float4 s4; s4.x = sv; s4.y = sv; s4.z = sv; s4.w = sv;
            *(float4*)(srcp + off) = s4;
            *(float4*)(dstp + off) = dst4;
        }

        // all waves done READING the LDS tile -> safe to overwrite
        RAWBAR();

        if (have) {
            STAGE(l0, l1, l2, l3);
        }
        asm volatile("s_waitcnt lgkmcnt(0)" ::: "memory");
        RAWBAR();
    }
#undef COORDS
#undef LOADT
#undef STAGE
#undef RAWBAR
}

extern "C" void kernel_launch(void* const* d_in, const int* in_sizes, int n_in,
                              void* d_out, int out_size, void* d_ws, size_t ws_size,
                              hipStream_t stream) {
    const float* x     = (const float*)d_in[0];
    const float* Wm    = (const float*)d_in[1];
    const float* tptr  = (const float*)d_in[2];
    const float* thptr = (const float*)d_in[3];

    const int N = in_sizes[0] / FDIM;                       // 32768
    const long long rem = (long long)out_size - (long long)N * EMB;
    int G = (rem > 0) ? (int)((3LL * N * N) / rem) : 32;    // 32
    if (G <= 0) G = 32;
    const int n = N / G;                                    // 1024
    const int nb = n / 32;

    float* out  = (float*)d_out;
    float* xe   = out;
    const long long M = (long long)G * n * n;
    float* srcp = out + (size_t)N * EMB;
    float* dstp = srcp + (size_t)M;
    float* wts  = dstp + (size_t)M;

    float* stats = (float*)d_ws;
    float* psum  = stats + 64;
    float* pmin  = psum + (size_t)nb * 32;
    float* pmax  = pmin + (size_t)nb * 32;

    k_gemm<<<N / 128, 256, 0, stream>>>(x, Wm, xe);
    k_stats_a<<<nb, 256, 0, stream>>>(xe, psum, pmin, pmax);
    k_stats_b<<<1, 64, 0, stream>>>(psum, pmin, pmax, nb, n, stats);

    const int tprow = n / 64;
    const int ntiles = tprow * tprow * G;                   // 8192
    const int nblocks = 1024;                               // 4 blocks/CU resident
    const int tpb = (ntiles + nblocks - 1) / nblocks;       // 8
    k_edges_p<<<nblocks, 256, 0, stream>>>(xe, stats, tptr, thptr,
                                           wts, srcp, dstp, n, ntiles, tpb);
}

// Round 8
// 99.889 us; speedup vs baseline: 1.1466x; 1.1466x over previous
//
#include <hip/hip_runtime.h>

#define FDIM 128
#define EMB 32

typedef __attribute__((ext_vector_type(4))) float f32x4;

static __device__ __forceinline__ void store_nt(float* p, float4 v) {
    f32x4 w; w.x = v.x; w.y = v.y; w.z = v.z; w.w = v.w;
    __builtin_nontemporal_store(w, (f32x4*)p);
}

// ---------------- K1: xe = x @ W  (f32 in, f32 out) ----------------
__global__ __launch_bounds__(256) void k_gemm(const float* __restrict__ x,
                                              const float* __restrict__ Wm,
                                              float* __restrict__ xe) {
    __shared__ float sW[FDIM * EMB]; // [k][e] row-major, 16 KiB
    const int t = threadIdx.x;
#pragma unroll
    for (int i = 0; i < (FDIM * EMB) / (256 * 4); ++i) {
        int idx = (t + i * 256) * 4;
        *(float4*)(sW + idx) = *(const float4*)(Wm + idx);
    }
    __syncthreads();

    const int r0 = blockIdx.x * 128 + (t >> 3) * 4;
    const int e0 = (t & 7) * 4;

    float acc[4][4];
#pragma unroll
    for (int i = 0; i < 4; ++i)
#pragma unroll
        for (int j = 0; j < 4; ++j) acc[i][j] = 0.f;

    for (int k = 0; k < FDIM; k += 4) {
        float4 w0 = *(const float4*)(sW + (k + 0) * EMB + e0);
        float4 w1 = *(const float4*)(sW + (k + 1) * EMB + e0);
        float4 w2 = *(const float4*)(sW + (k + 2) * EMB + e0);
        float4 w3 = *(const float4*)(sW + (k + 3) * EMB + e0);
#pragma unroll
        for (int rr = 0; rr < 4; ++rr) {
            float4 xq = *(const float4*)(x + (size_t)(r0 + rr) * FDIM + k);
            acc[rr][0] += xq.x * w0.x + xq.y * w1.x + xq.z * w2.x + xq.w * w3.x;
            acc[rr][1] += xq.x * w0.y + xq.y * w1.y + xq.z * w2.y + xq.w * w3.y;
            acc[rr][2] += xq.x * w0.z + xq.y * w1.z + xq.z * w2.z + xq.w * w3.z;
            acc[rr][3] += xq.x * w0.w + xq.y * w1.w + xq.z * w2.w + xq.w * w3.w;
        }
    }

#pragma unroll
    for (int rr = 0; rr < 4; ++rr) {
        const size_t r = (size_t)(r0 + rr);
        float4 o; o.x = acc[rr][0]; o.y = acc[rr][1]; o.z = acc[rr][2]; o.w = acc[rr][3];
        *(float4*)(xe + r * EMB + e0) = o;   // keep cached: consumed by stats/edges
    }
}

// ---------------- K2a: per-block partial sum/min/max over graph-0 rows ----------------
__global__ __launch_bounds__(256) void k_stats_a(const float* __restrict__ xe,
                                                 float* __restrict__ psum,
                                                 float* __restrict__ pmin,
                                                 float* __restrict__ pmax) {
    __shared__ float rs[256], rmn[256], rmx[256];
    const int t = threadIdx.x;
    const int d = t & 31, rg = t >> 5;
    const int r0 = blockIdx.x * 32;

    float s = 0.f, mn = 3.4e38f, mx = -3.4e38f;
#pragma unroll
    for (int it = 0; it < 4; ++it) {
        float v = xe[(size_t)(r0 + rg + it * 8) * EMB + d];
        s += v; mn = fminf(mn, v); mx = fmaxf(mx, v);
    }
    rs[t] = s; rmn[t] = mn; rmx[t] = mx;
    __syncthreads();
#pragma unroll
    for (int st = 128; st >= 32; st >>= 1) {
        if (t < st) {
            rs[t] += rs[t + st];
            rmn[t] = fminf(rmn[t], rmn[t + st]);
            rmx[t] = fmaxf(rmx[t], rmx[t + st]);
        }
        __syncthreads();
    }
    if (t < 32) {
        psum[blockIdx.x * 32 + t] = rs[t];
        pmin[blockIdx.x * 32 + t] = rmn[t];
        pmax[blockIdx.x * 32 + t] = rmx[t];
    }
}

// ---------------- K2b: finalize centroid + scale ----------------
__global__ __launch_bounds__(64) void k_stats_b(const float* __restrict__ psum,
                                                const float* __restrict__ pmin,
                                                const float* __restrict__ pmax,
                                                int nb, int n,
                                                float* __restrict__ stats) {
    const int t = threadIdx.x;
    const int d = t & 31;
    float s = 0.f, mn = 3.4e38f, mx = -3.4e38f;
    for (int b = 0; b < nb; ++b) {
        s += psum[b * 32 + d];
        mn = fminf(mn, pmin[b * 32 + d]);
        mx = fmaxf(mx, pmax[b * 32 + d]);
    }
    const float c = s / (float)n;
    float dev = fmaxf(mx - c, c - mn);
#pragma unroll
    for (int off = 16; off >= 1; off >>= 1)
        dev = fmaxf(dev, __shfl_xor(dev, off, 32));
    if (t < 32) stats[t] = c;
    if (t == 0) stats[EMB] = 0.9f / dev;
}

// ---------------- K3: fused pairwise D -> sigmoid + edge_index fill ----------------
// grid (n/64, n/64, G); block 256; 64x64 tile; thread owns 4 rows x 4
// consecutive cols -> float4 nt-stores (no L2 allocate: keeps xe resident).
// shB XOR-swizzled (d ^= ((row>>2)&7)<<2) for conflict-free B-reads.
#define LDST 36
__global__ __launch_bounds__(256) void k_edges(const float* __restrict__ xe,
                                               const float* __restrict__ stats,
                                               const float* __restrict__ tptr,
                                               const float* __restrict__ thptr,
                                               float* __restrict__ wts,
                                               float* __restrict__ srcp,
                                               float* __restrict__ dstp,
                                               int n) {
    __shared__ float shA[64 * LDST];
    __shared__ float shB[64 * LDST];
    __shared__ float sqA[64], sqB[64];

    const int g = blockIdx.z;
    const int i0 = blockIdx.y * 64, j0 = blockIdx.x * 64;
    const int t = threadIdx.x;
    const float scale = stats[EMB];

    const float* baseA = xe + ((size_t)g * n + i0) * EMB;
    const float* baseB = xe + ((size_t)g * n + j0) * EMB;

#pragma unroll
    for (int c = 0; c < 2; ++c) {
        int id = t + c * 256;
        int row = id >> 3;
        int dc = (id & 7) * 4;
        int dswz = dc ^ (((row >> 2) & 7) << 2);
        float4 cen = *(const float4*)(stats + dc);
        float4 va = *(const float4*)(baseA + (size_t)row * EMB + dc);
        float4 vb = *(const float4*)(baseB + (size_t)row * EMB + dc);
        va.x = (va.x - cen.x) * scale; va.y = (va.y - cen.y) * scale;
        va.z = (va.z - cen.z) * scale; va.w = (va.w - cen.w) * scale;
        vb.x = (vb.x - cen.x) * scale; vb.y = (vb.y - cen.y) * scale;
        vb.z = (vb.z - cen.z) * scale; vb.w = (vb.w - cen.w) * scale;
        *(float4*)(shA + row * LDST + dc) = va;
        *(float4*)(shB + row * LDST + dswz) = vb;
    }
    __syncthreads();

    if (t < 64) {
        float s = 0.f;
#pragma unroll
        for (int d = 0; d < EMB; d += 4) {
            float4 v = *(const float4*)(shA + t * LDST + d);
            s += v.x * v.x + v.y * v.y + v.z * v.z + v.w * v.w;
        }
        sqA[t] = s;
    } else if (t < 128) {
        int r = t - 64;
        int key = ((r >> 2) & 7) << 2;
        float s = 0.f;
#pragma unroll
        for (int d = 0; d < EMB; d += 4) {
            float4 v = *(const float4*)(shB + r * LDST + (d ^ key));
            s += v.x * v.x + v.y * v.y + v.z * v.z + v.w * v.w;
        }
        sqB[r] = s;
    }
    __syncthreads();

    const int ti = t >> 4, tj = t & 15;
    const int bkey = (tj & 7) << 2;
    float acc[4][4];
#pragma unroll
    for (int i = 0; i < 4; ++i)
#pragma unroll
        for (int j = 0; j < 4; ++j) acc[i][j] = 0.f;

    for (int d = 0; d < EMB; d += 4) {
        float4 a[4], b[4];
#pragma unroll
        for (int u = 0; u < 4; ++u)
            a[u] = *(const float4*)(shA + (ti * 4 + u) * LDST + d);
        const int dsw = d ^ bkey;
#pragma unroll
        for (int v = 0; v < 4; ++v)
            b[v] = *(const float4*)(shB + (tj * 4 + v) * LDST + dsw);
#pragma unroll
        for (int u = 0; u < 4; ++u)
#pragma unroll
            for (int v = 0; v < 4; ++v)
                acc[u][v] += a[u].x * b[v].x + a[u].y * b[v].y +
                             a[u].z * b[v].z + a[u].w * b[v].w;
    }

    const float T = *tptr;
    const float TH = fabsf(*thptr);
    const int gn = g * n;
    const size_t gbase = (size_t)g * n * n;

    const float4 sq4 = *(const float4*)(sqB + tj * 4);
    const float dbase = (float)(gn + j0 + tj * 4);
    float4 dst4; dst4.x = dbase; dst4.y = dbase + 1.f; dst4.z = dbase + 2.f; dst4.w = dbase + 3.f;

#pragma unroll
    for (int u = 0; u < 4; ++u) {
        const int row = i0 + ti * 4 + u;
        const float sa = sqA[ti * 4 + u];
        const size_t off = gbase + (size_t)row * n + j0 + tj * 4;

        float4 w;
        {
            float D0 = fmaxf(sa + sq4.x - 2.f * acc[u][0], 0.f);
            float D1 = fmaxf(sa + sq4.y - 2.f * acc[u][1], 0.f);
            float D2 = fmaxf(sa + sq4.z - 2.f * acc[u][2], 0.f);
            float D3 = fmaxf(sa + sq4.w - 2.f * acc[u][3], 0.f);
            w.x = __builtin_amdgcn_rcpf(1.f + __expf(-(T * (TH - D0))));
            w.y = __builtin_amdgcn_rcpf(1.f + __expf(-(T * (TH - D1))));
            w.z = __builtin_amdgcn_rcpf(1.f + __expf(-(T * (TH - D2))));
            w.w = __builtin_amdgcn_rcpf(1.f + __expf(-(T * (TH - D3))));
        }
        store_nt(wts + off, w);

        const float sv = (float)(gn + row);
        float4 s4; s4.x = sv; s4.y = sv; s4.z = sv; s4.w = sv;
        store_nt(srcp + off, s4);
        store_nt(dstp + off, dst4);
    }
}

extern "C" void kernel_launch(void* const* d_in, const int* in_sizes, int n_in,
                              void* d_out, int out_size, void* d_ws, size_t ws_size,
                              hipStream_t stream) {
    const float* x     = (const float*)d_in[0];
    const float* Wm    = (const float*)d_in[1];
    const float* tptr  = (const float*)d_in[2];
    const float* thptr = (const float*)d_in[3];

    const int N = in_sizes[0] / FDIM;                       // 32768
    const long long rem = (long long)out_size - (long long)N * EMB;
    int G = (rem > 0) ? (int)((3LL * N * N) / rem) : 32;    // 32
    if (G <= 0) G = 32;
    const int n = N / G;                                    // 1024
    const int nb = n / 32;

    float* out  = (float*)d_out;
    float* xe   = out;
    const long long M = (long long)G * n * n;
    float* srcp = out + (size_t)N * EMB;
    float* dstp = srcp + (size_t)M;
    float* wts  = dstp + (size_t)M;

    float* stats = (float*)d_ws;
    float* psum  = stats + 64;
    float* pmin  = psum + (size_t)nb * 32;
    float* pmax  = pmin + (size_t)nb * 32;

    k_gemm<<<N / 128, 256, 0, stream>>>(x, Wm, xe);
    k_stats_a<<<nb, 256, 0, stream>>>(xe, psum, pmin, pmax);
    k_stats_b<<<1, 64, 0, stream>>>(psum, pmin, pmax, nb, n, stats);
    dim3 ge(n / 64, n / 64, G);
    k_edges<<<ge, 256, 0, stream>>>(xe, stats, tptr, thptr, wts, srcp, dstp, n);
}